// Round 11
// baseline (248.866 us; speedup 1.0000x reference)
//
#include <hip/hip_runtime.h>
#include <math.h>

// ---------- types ----------
typedef __attribute__((ext_vector_type(8))) short short8;
typedef __attribute__((ext_vector_type(4))) short short4v;
typedef __attribute__((ext_vector_type(4))) float f32x4;
typedef __attribute__((ext_vector_type(2))) float f32x2;

#if __has_builtin(__builtin_amdgcn_mfma_f32_16x16x16bf16_1k)
#define HAVE_MFMA16 1
#else
#define HAVE_MFMA16 0
#endif

// bf16 RNE helpers
__device__ __forceinline__ short f2bf(float f) {
  union { float f; unsigned u; } x; x.f = f;
  unsigned r = x.u + 0x7fffu + ((x.u >> 16) & 1u);
  return (short)(r >> 16);
}
#if __has_builtin(__builtin_amdgcn_cvt_pk_bf16_f32)
typedef __attribute__((ext_vector_type(2))) __bf16 bf16x2;
__device__ __forceinline__ unsigned pack_bf(float a, float b) {
  union { bf16x2 v; unsigned u; } t;
  t.v = __builtin_amdgcn_cvt_pk_bf16_f32(a, b);
  return t.u;
}
#else
__device__ __forceinline__ unsigned pack_bf(float a, float b) {
  union { float f; unsigned u; } x, y; x.f = a; y.f = b;
  unsigned ra = x.u + 0x7fffu + ((x.u >> 16) & 1u);
  unsigned rb = y.u + 0x7fffu + ((y.u >> 16) & 1u);
  return (ra >> 16) | (rb & 0xffff0000u);
}
#endif
__device__ __forceinline__ float fast_exp2(float x) {
#if __has_builtin(__builtin_amdgcn_exp2f)
  return __builtin_amdgcn_exp2f(x);
#else
  return exp2f(x);
#endif
}
union U4S8 { unsigned u[4]; short8 s; };
union U2S4 { unsigned u[2]; short4v s; };

// async global->LDS, 16B/lane: wave-uniform LDS base, HW scatters lane i at base+i*16B.
__device__ __forceinline__ void async16(const short* g, short* lds_uniform) {
  __builtin_amdgcn_global_load_lds(
      (const __attribute__((address_space(1))) void*)g,
      (__attribute__((address_space(3))) void*)lds_uniform, 16, 0, 0);
}

// ---------- weight convert+transpose: T[n][k] = bf16(W[k][n]), 1024x1024 ----------
__global__ __launch_bounds__(256) void wconv(
    const float* __restrict__ W0, const float* __restrict__ W1,
    const float* __restrict__ W2, const float* __restrict__ W3,
    short* __restrict__ T0, short* __restrict__ T1,
    short* __restrict__ T2, short* __restrict__ T3) {
  const float* W; short* T;
  switch (blockIdx.z) {
    case 0: W = W0; T = T0; break;
    case 1: W = W1; T = T1; break;
    case 2: W = W2; T = T2; break;
    default: W = W3; T = T3; break;
  }
  __shared__ __align__(16) short t[64][72];
  const int tid = threadIdx.x;
  const int x0 = blockIdx.x * 64, y0 = blockIdx.y * 64;
  {
    int rr = tid >> 2, cc = (tid & 3) * 16;
    const float* p = W + (size_t)(x0 + rr) * 1024 + y0 + cc;
    f32x4 v[4];
    v[0] = *(const f32x4*)(p + 0);  v[1] = *(const f32x4*)(p + 4);
    v[2] = *(const f32x4*)(p + 8);  v[3] = *(const f32x4*)(p + 12);
#pragma unroll
    for (int i = 0; i < 4; ++i)
#pragma unroll
      for (int j = 0; j < 4; ++j)
        t[cc + 4 * i + j][rr] = f2bf(v[i][j]);
  }
  __syncthreads();
  {
    int nr = tid >> 2, kc = (tid & 3) * 16;
    short* q = T + (size_t)(y0 + nr) * 1024 + x0 + kc;
    *(short8*)q       = *(const short8*)&t[nr][kc];
    *(short8*)(q + 8) = *(const short8*)&t[nr][kc + 8];
  }
}

// ---------- activation convert: Y = bf16(X), 4M elements each ----------
__global__ __launch_bounds__(256) void aconv(
    const float* __restrict__ X0, const float* __restrict__ X1, const float* __restrict__ X2,
    short* __restrict__ Y0, short* __restrict__ Y1, short* __restrict__ Y2) {
  const float* X; short* Y;
  switch (blockIdx.z) {
    case 0: X = X0; Y = Y0; break;
    case 1: X = X1; Y = Y1; break;
    default: X = X2; Y = Y2; break;
  }
  size_t idx = ((size_t)blockIdx.x * 256 + threadIdx.x) * 16;
  f32x4 v0 = *(const f32x4*)(X + idx + 0);
  f32x4 v1 = *(const f32x4*)(X + idx + 4);
  f32x4 v2 = *(const f32x4*)(X + idx + 8);
  f32x4 v3 = *(const f32x4*)(X + idx + 12);
  U4S8 a, b;
  a.u[0] = pack_bf(v0[0], v0[1]); a.u[1] = pack_bf(v0[2], v0[3]);
  a.u[2] = pack_bf(v1[0], v1[1]); a.u[3] = pack_bf(v1[2], v1[3]);
  b.u[0] = pack_bf(v2[0], v2[1]); b.u[1] = pack_bf(v2[2], v2[3]);
  b.u[2] = pack_bf(v3[0], v3[1]); b.u[3] = pack_bf(v3[2], v3[3]);
  *(short8*)(Y + idx) = a.s;
  *(short8*)(Y + idx + 8) = b.s;
}

// ---------- async GEMM (m97 structure): C = (A@B^T + bias)*scale, all-bf16 in, fp32 acc ----------
template <bool OUT_F32, int BM>
__global__ __launch_bounds__(256) void gemm_async(
    const short* __restrict__ A0, const short* __restrict__ A1, const short* __restrict__ A2,
    const short* __restrict__ B0, const short* __restrict__ B1, const short* __restrict__ B2,
    const float* __restrict__ b0, const float* __restrict__ b1, const float* __restrict__ b2,
    void* __restrict__ C0, void* __restrict__ C1, void* __restrict__ C2,
    float s0, float s1, float s2, int M, int N, int K) {
  const int z = blockIdx.z;
  const short* A    = z == 0 ? A0 : (z == 1 ? A1 : A2);
  const short* B    = z == 0 ? B0 : (z == 1 ? B1 : B2);
  const float* bias = z == 0 ? b0 : (z == 1 ? b1 : b2);
  void*        Cv   = z == 0 ? C0 : (z == 1 ? C1 : C2);
  const float  cs   = z == 0 ? s0 : (z == 1 ? s1 : s2);

  constexpr int MF = BM / 32;
  constexpr int AJ = BM / 64;
  __shared__ __align__(16) short As[BM * 32];
  __shared__ __align__(16) short Bs[128 * 32];
  const int tid = threadIdx.x;
  const int l = tid & 63, w = tid >> 6;
  const int lr = l & 15, lq = l >> 4;
  const int lin = blockIdx.x + (int)gridDim.x * blockIdx.y;
  const int ny = (int)gridDim.y;
  const int yb = lin % ny, xb = lin / ny;
  const int m0 = yb * BM, n0 = xb * 128;
  const int wm = (w >> 1) * (BM / 2), wn = (w & 1) * 64;
  f32x4 acc[MF][4] = {};

  const int lrow = l >> 2, lcol = (l & 3) * 8;
  const short* aptr[AJ];
  short* alds[AJ];
#pragma unroll
  for (int j = 0; j < AJ; ++j) {
    int chunk = w * AJ + j;
    aptr[j] = A + (size_t)(m0 + chunk * 16 + lrow) * K + lcol;
    alds[j] = &As[chunk * 512];
  }
  const short* bptr[2];
  short* blds[2];
#pragma unroll
  for (int j = 0; j < 2; ++j) {
    int chunk = w * 2 + j;
    bptr[j] = B + (size_t)(n0 + chunk * 16 + lrow) * K + lcol;
    blds[j] = &Bs[chunk * 512];
  }

  const int KT = K >> 5;
  for (int kt = 0; kt < KT; ++kt) {
    const int k0 = kt * 32;
    __syncthreads();
#pragma unroll
    for (int j = 0; j < AJ; ++j) async16(aptr[j] + k0, alds[j]);
#pragma unroll
    for (int j = 0; j < 2; ++j) async16(bptr[j] + k0, blds[j]);
    __syncthreads();

    short8 af[MF], bfr[4];
#pragma unroll
    for (int i = 0; i < MF; ++i)
      af[i] = *(const short8*)&As[(wm + i * 16 + lr) * 32 + lq * 8];
#pragma unroll
    for (int i = 0; i < 4; ++i)
      bfr[i] = *(const short8*)&Bs[(wn + i * 16 + lr) * 32 + lq * 8];
#pragma unroll
    for (int mi = 0; mi < MF; ++mi)
#pragma unroll
      for (int ni = 0; ni < 4; ++ni)
        acc[mi][ni] = __builtin_amdgcn_mfma_f32_16x16x32_bf16(af[mi], bfr[ni], acc[mi][ni], 0, 0, 0);
  }

#pragma unroll
  for (int ni = 0; ni < 4; ++ni) {
    int gn = n0 + wn + ni * 16 + lr;
    float bv = bias[gn];
#pragma unroll
    for (int mi = 0; mi < MF; ++mi) {
      int gm = m0 + wm + mi * 16 + lq * 4;
#pragma unroll
      for (int r = 0; r < 4; ++r) {
        float val = (acc[mi][ni][r] + bv) * cs;
        if constexpr (OUT_F32)
          ((float*)Cv)[(size_t)(gm + r) * N + gn] = val;
        else
          ((short*)Cv)[(size_t)(gm + r) * N + gn] = f2bf(val);
      }
    }
  }
}

// ---------- fallback GEMM (round-9 verified): reg-dbuf, A fp32 or bf16 ----------
template <bool A_IS_F32, bool B_IS_BF16, bool OUT_F32, int BM>
__global__ __launch_bounds__(256) void gemm_bias(
    const void* __restrict__ A0, const void* __restrict__ A1, const void* __restrict__ A2,
    const void* __restrict__ B0, const void* __restrict__ B1, const void* __restrict__ B2,
    const float* __restrict__ b0, const float* __restrict__ b1, const float* __restrict__ b2,
    void* __restrict__ C0, void* __restrict__ C1, void* __restrict__ C2,
    float s0, float s1, float s2, int M, int N, int K) {
  const int z = blockIdx.z;
  const void*  Av   = z == 0 ? A0 : (z == 1 ? A1 : A2);
  const void*  Bv   = z == 0 ? B0 : (z == 1 ? B1 : B2);
  const float* bias = z == 0 ? b0 : (z == 1 ? b1 : b2);
  void*        Cv   = z == 0 ? C0 : (z == 1 ? C1 : C2);
  const float  cs   = z == 0 ? s0 : (z == 1 ? s1 : s2);

  constexpr int MF = BM / 32;
  __shared__ __align__(16) short As[BM * 40];
  __shared__ __align__(16) short Bs[128 * 40];
  const int tid = threadIdx.x;
  const int l = tid & 63, w = tid >> 6;
  const int lr = l & 15, lq = l >> 4;
  const int lin = blockIdx.x + (int)gridDim.x * blockIdx.y;
  const int ny = (int)gridDim.y;
  const int yb = lin % ny, xb = lin / ny;
  const int m0 = yb * BM, n0 = xb * 128;
  const int wm = (w >> 1) * (BM / 2), wn = (w & 1) * 64;
  f32x4 acc[MF][4] = {};

  constexpr int TPR = 256 / BM;
  const int ar = tid / TPR, ac = (tid % TPR) * (32 / TPR);
  const int br = tid >> 1, bcc = (tid & 1) * 16;
  const int dp = tid & 63, kb = tid >> 6;

  f32x4 avf[MF];
  short8 avb[BM / 64 > 0 ? BM / 64 : 1];
  short8 bvb[2];
  f32x2 bvf[8];

  auto load_regs = [&](int k0) {
    if constexpr (A_IS_F32) {
      const float* Ap = (const float*)Av + (size_t)(m0 + ar) * K + k0 + ac;
#pragma unroll
      for (int i = 0; i < MF; ++i) avf[i] = *(const f32x4*)(Ap + 4 * i);
    } else {
      const short* Ap = (const short*)Av + (size_t)(m0 + ar) * K + k0 + ac;
#pragma unroll
      for (int i = 0; i < BM / 64; ++i) avb[i] = *(const short8*)(Ap + 8 * i);
    }
    if constexpr (B_IS_BF16) {
      const short* Bp = (const short*)Bv + (size_t)(n0 + br) * K + k0 + bcc;
      bvb[0] = *(const short8*)(Bp + 0);
      bvb[1] = *(const short8*)(Bp + 8);
    } else {
      const float* Bp = (const float*)Bv + (size_t)(k0 + kb * 8) * N + n0 + 2 * dp;
#pragma unroll
      for (int i = 0; i < 4; ++i) {
        bvf[2 * i]     = *(const f32x2*)(Bp + (size_t)(2 * i) * N);
        bvf[2 * i + 1] = *(const f32x2*)(Bp + (size_t)(2 * i + 1) * N);
      }
    }
  };
  auto write_lds = [&]() {
    if constexpr (A_IS_F32) {
#pragma unroll
      for (int j = 0; j < MF / 2; ++j) {
        U4S8 p;
        p.u[0] = pack_bf(avf[2 * j][0], avf[2 * j][1]);
        p.u[1] = pack_bf(avf[2 * j][2], avf[2 * j][3]);
        p.u[2] = pack_bf(avf[2 * j + 1][0], avf[2 * j + 1][1]);
        p.u[3] = pack_bf(avf[2 * j + 1][2], avf[2 * j + 1][3]);
        *(short8*)&As[ar * 40 + ac + 8 * j] = p.s;
      }
    } else {
#pragma unroll
      for (int j = 0; j < BM / 64; ++j)
        *(short8*)&As[ar * 40 + ac + 8 * j] = avb[j];
    }
    if constexpr (B_IS_BF16) {
      *(short8*)&Bs[br * 40 + bcc] = bvb[0];
      *(short8*)&Bs[br * 40 + bcc + 8] = bvb[1];
    } else {
      U4S8 lo, hi;
#pragma unroll
      for (int i = 0; i < 4; ++i) {
        lo.u[i] = pack_bf(bvf[2 * i][0], bvf[2 * i + 1][0]);
        hi.u[i] = pack_bf(bvf[2 * i][1], bvf[2 * i + 1][1]);
      }
      *(short8*)&Bs[(2 * dp) * 40 + kb * 8] = lo.s;
      *(short8*)&Bs[(2 * dp + 1) * 40 + kb * 8] = hi.s;
    }
  };

  load_regs(0);
  const int KT = K >> 5;
  for (int kt = 0; kt < KT; ++kt) {
    write_lds();
    __syncthreads();
    if (kt + 1 < KT) load_regs((kt + 1) * 32);

    short8 af[MF], bfr[4];
#pragma unroll
    for (int i = 0; i < MF; ++i)
      af[i] = *(const short8*)&As[(wm + i * 16 + lr) * 40 + lq * 8];
#pragma unroll
    for (int i = 0; i < 4; ++i)
      bfr[i] = *(const short8*)&Bs[(wn + i * 16 + lr) * 40 + lq * 8];
#pragma unroll
    for (int mi = 0; mi < MF; ++mi)
#pragma unroll
      for (int ni = 0; ni < 4; ++ni)
        acc[mi][ni] = __builtin_amdgcn_mfma_f32_16x16x32_bf16(af[mi], bfr[ni], acc[mi][ni], 0, 0, 0);
    __syncthreads();
  }

#pragma unroll
  for (int ni = 0; ni < 4; ++ni) {
    int gn = n0 + wn + ni * 16 + lr;
    float bv = bias[gn];
#pragma unroll
    for (int mi = 0; mi < MF; ++mi) {
      int gm = m0 + wm + mi * 16 + lq * 4;
#pragma unroll
      for (int r = 0; r < 4; ++r) {
        float val = (acc[mi][ni][r] + bv) * cs;
        if constexpr (OUT_F32)
          ((float*)Cv)[(size_t)(gm + r) * N + gn] = val;
        else
          ((short*)Cv)[(size_t)(gm + r) * N + gn] = f2bf(val);
      }
    }
  }
}

// ---------- flash attention: q-tile 64 (1024 blocks = 4/CU), no-max softmax ----------
// Q pre-scaled by 0.125*log2(e) -> p = 2^s. S' = K·Q^T (C-layout == mfma16 A-frag layout).
// Vt stores use bank-swizzle: col block p = (c + (d>>3)) & 7 -> conflict-free b128 writes.
__global__ __launch_bounds__(256) void attn64(
    const short* __restrict__ Q, const short* __restrict__ K,
    const short* __restrict__ V, short* __restrict__ ctx) {
  __shared__ __align__(16) short Ks[64][72];   // [kpos][d]
  __shared__ __align__(16) short Vt[64][72];   // [d][kpos], block-swizzled
#if !HAVE_MFMA16
  __shared__ __align__(16) short Ps2[4][16][68];
#endif
  const int tid = threadIdx.x, l = tid & 63, w = tid >> 6;
  const int lr = l & 15, lq = l >> 4;
  // swizzle: h = lin & 15 -> same h => same XCD (lin mod 8 fixed)
  const int lin = blockIdx.x + 32 * blockIdx.y;
  const int h = lin & 15, qblk = lin >> 4;
  const int b = blockIdx.z, q0 = qblk * 64;
  const size_t bh = (size_t)b * 2048 * 1024 + (size_t)h * 64;
  const short* Kg = K + bh;
  const short* Vg = V + bh;

  // Q B-frags (once): wave w owns q rows [w*16, w*16+16)
  short8 qb[2];
#pragma unroll
  for (int ks = 0; ks < 2; ++ks)
    qb[ks] = *(const short8*)&Q[bh + (size_t)(q0 + w * 16 + lr) * 1024 + ks * 32 + lq * 8];

  f32x4 accO[4] = {};
  float lpart = 0.f;

  const int kr = tid >> 2, kc = (tid & 3) * 16;
  const int vdp = tid & 31, vkb = tid >> 5;
  const int vswz = ((vkb + (vdp >> 2)) & 7) * 8;  // swizzled col block for Vt writes

  short8 kv0, kv1;
  unsigned vu[8];
  auto load_kv = [&](int kt) {
    const short* Kp = &Kg[(size_t)(kt * 64 + kr) * 1024 + kc];
    kv0 = *(const short8*)(Kp + 0);
    kv1 = *(const short8*)(Kp + 8);
#pragma unroll
    for (int i = 0; i < 8; ++i)
      vu[i] = *(const unsigned*)&Vg[(size_t)(kt * 64 + vkb * 8 + i) * 1024 + vdp * 2];
  };
  auto write_kv = [&]() {
    *(short8*)&Ks[kr][kc] = kv0;
    *(short8*)&Ks[kr][kc + 8] = kv1;
    U4S8 lo, hi;
#pragma unroll
    for (int j = 0; j < 4; ++j) {
      lo.u[j] = (vu[2 * j] & 0xffffu) | (vu[2 * j + 1] << 16);       // d = 2*vdp
      hi.u[j] = (vu[2 * j] >> 16) | (vu[2 * j + 1] & 0xffff0000u);  // d = 2*vdp+1
    }
    *(short8*)&Vt[2 * vdp][vswz] = lo.s;
    *(short8*)&Vt[2 * vdp + 1][vswz] = hi.s;
  };

  load_kv(0);
  for (int kt = 0; kt < 32; ++kt) {
    write_kv();
    __syncthreads();
    if (kt + 1 < 32) load_kv(kt + 1);

    // S' = K·Q^T
    short8 ka[4][2];
#pragma unroll
    for (int ni = 0; ni < 4; ++ni)
#pragma unroll
      for (int ks = 0; ks < 2; ++ks)
        ka[ni][ks] = *(const short8*)&Ks[ni * 16 + lr][ks * 32 + lq * 8];
    f32x4 s[4] = {};
#pragma unroll
    for (int ni = 0; ni < 4; ++ni) {
      s[ni] = __builtin_amdgcn_mfma_f32_16x16x32_bf16(ka[ni][0], qb[0], s[ni], 0, 0, 0);
      s[ni] = __builtin_amdgcn_mfma_f32_16x16x32_bf16(ka[ni][1], qb[1], s[ni], 0, 0, 0);
    }

    // p = 2^s, pack bf16
    unsigned pk[4][2];
#pragma unroll
    for (int ni = 0; ni < 4; ++ni) {
      float p0 = fast_exp2(s[ni][0]);
      float p1 = fast_exp2(s[ni][1]);
      float p2 = fast_exp2(s[ni][2]);
      float p3 = fast_exp2(s[ni][3]);
      lpart += (p0 + p1) + (p2 + p3);
      pk[ni][0] = pack_bf(p0, p1);
      pk[ni][1] = pack_bf(p2, p3);
    }

#if HAVE_MFMA16
#pragma unroll
    for (int di = 0; di < 4; ++di) {
      const int dR = di * 16 + lr;
      const int ud = 2 * di + (lr >> 3);
#pragma unroll
      for (int ni = 0; ni < 4; ++ni) {
        const int pb = ((2 * ni + (lq >> 1) + ud) & 7) * 8 + (lq & 1) * 4;
        short4v vb = *(const short4v*)&Vt[dR][pb];
        U2S4 a; a.u[0] = pk[ni][0]; a.u[1] = pk[ni][1];
        accO[di] = __builtin_amdgcn_mfma_f32_16x16x16bf16_1k(a.s, vb, accO[di], 0, 0, 0);
      }
    }
#else
#pragma unroll
    for (int ni = 0; ni < 4; ++ni) {
      unsigned* dst = (unsigned*)&Ps2[w][lr][16 * ni + 4 * lq];
      dst[0] = pk[ni][0];
      dst[1] = pk[ni][1];
    }
#pragma unroll
    for (int ks = 0; ks < 2; ++ks) {
      const short* src = &Ps2[w][lr][32 * ks + 8 * lq];
      U4S8 a;
      a.u[0] = ((const unsigned*)src)[0]; a.u[1] = ((const unsigned*)src)[1];
      a.u[2] = ((const unsigned*)src)[2]; a.u[3] = ((const unsigned*)src)[3];
#pragma unroll
      for (int di = 0; di < 4; ++di) {
        const int dR = di * 16 + lr;
        const int ud = 2 * di + (lr >> 3);
        const int pb = ((4 * ks + lq + ud) & 7) * 8;
        short8 vb = *(const short8*)&Vt[dR][pb];
        accO[di] = __builtin_amdgcn_mfma_f32_16x16x32_bf16(a.s, vb, accO[di], 0, 0, 0);
      }
    }
#endif
    __syncthreads();
  }

  // l: combine 4 lq replicas; redistribute to C-layout rows
  lpart += __shfl_xor(lpart, 16, 64);
  lpart += __shfl_xor(lpart, 32, 64);
  float inv = 1.0f / lpart;
  float ir[4];
#pragma unroll
  for (int r = 0; r < 4; ++r)
    ir[r] = __shfl(inv, 4 * lq + r, 64);

#pragma unroll
  for (int r = 0; r < 4; ++r) {
    size_t row = bh + (size_t)(q0 + w * 16 + 4 * lq + r) * 1024;
#pragma unroll
    for (int di = 0; di < 4; ++di)
      ctx[row + di * 16 + lr] = f2bf(accO[di][r] * ir[r]);
  }
}

// ---------- launch ----------
extern "C" void kernel_launch(void* const* d_in, const int* in_sizes, int n_in,
                              void* d_out, int out_size, void* d_ws, size_t ws_size,
                              hipStream_t stream) {
  const void*  query = d_in[0];
  const void*  key   = d_in[1];
  const void*  value = d_in[2];
  const float* Wq = (const float*)d_in[3];
  const float* bq = (const float*)d_in[4];
  const float* Wk = (const float*)d_in[5];
  const float* bk = (const float*)d_in[6];
  const float* Wv = (const float*)d_in[7];
  const float* bv = (const float*)d_in[8];
  const float* Wo = (const float*)d_in[9];
  const float* bo = (const float*)d_in[10];

  short* ws = (short*)d_ws;
  const size_t MT = 4096ull * 1024ull;
  const size_t WSZ = 1024ull * 1024ull;
  const float qscale = 0.125f * 1.4426950408889634f;

  short* Qb = ws;
  short* Vb = ws + MT;
  short* Kb = (short*)d_out;

  const bool turbo = ws_size >= (4 * MT + 4 * WSZ) * sizeof(short);  // 40 MB

  if (turbo) {
    short* Qcv = ws + 2 * MT;
    short* Vcv = ws + 3 * MT;
    short* Kcv = (short*)d_out + MT;
    short* WqT = ws + 4 * MT;
    short* WkT = WqT + WSZ;
    short* WvT = WqT + 2 * WSZ;
    short* WoT = WqT + 3 * WSZ;

    wconv<<<dim3(16, 16, 4), 256, 0, stream>>>(Wq, Wk, Wv, Wo, WqT, WkT, WvT, WoT);
    aconv<<<dim3(1024, 1, 3), 256, 0, stream>>>(
        (const float*)query, (const float*)key, (const float*)value, Qcv, Kcv, Vcv);
    gemm_async<false, 128><<<dim3(8, 32, 3), 256, 0, stream>>>(
        Qcv, Kcv, Vcv, WqT, WkT, WvT, bq, bk, bv, Qb, Kb, Vb,
        qscale, 1.0f, 1.0f, 4096, 1024, 1024);
    attn64<<<dim3(32, 16, 2), 256, 0, stream>>>(Qb, Kb, Vb, Qb);
    gemm_async<true, 64><<<dim3(8, 64, 1), 256, 0, stream>>>(
        Qb, Qb, Qb, WoT, WoT, WoT, bo, bo, bo, d_out, d_out, d_out,
        1.0f, 1.0f, 1.0f, 4096, 1024, 1024);
    return;
  }

  // ---- fallback: round-9 verified path ----
  const bool roomy = ws_size >= (2 * MT + 4 * WSZ) * sizeof(short);
  short *WqT, *WkT, *WvT, *WoT;
  if (roomy) {
    short* base = ws + 2 * MT;
    WqT = base; WkT = base + WSZ; WvT = base + 2 * WSZ; WoT = base + 3 * WSZ;
  } else {
    short* tail = (short*)d_out + MT;
    WqT = tail; WkT = tail + WSZ; WvT = tail + 2 * WSZ; WoT = nullptr;
  }

  wconv<<<dim3(16, 16, roomy ? 4 : 3), 256, 0, stream>>>(
      Wq, Wk, Wv, Wo, WqT, WkT, WvT, roomy ? WoT : WvT);

  gemm_bias<true, true, false, 128><<<dim3(8, 32, 3), 256, 0, stream>>>(
      query, key, value, WqT, WkT, WvT, bq, bk, bv, Qb, Kb, Vb,
      qscale, 1.0f, 1.0f, 4096, 1024, 1024);

  attn64<<<dim3(32, 16, 2), 256, 0, stream>>>(Qb, Kb, Vb, Qb);

  if (roomy)
    gemm_bias<false, true, true, 64><<<dim3(8, 64, 1), 256, 0, stream>>>(
        Qb, Qb, Qb, WoT, WoT, WoT, bo, bo, bo, d_out, d_out, d_out,
        1.0f, 1.0f, 1.0f, 4096, 1024, 1024);
  else
    gemm_bias<false, false, true, 64><<<dim3(8, 64, 1), 256, 0, stream>>>(
        Qb, Qb, Qb, Wo, Wo, Wo, bo, bo, bo, d_out, d_out, d_out,
        1.0f, 1.0f, 1.0f, 4096, 1024, 1024);
}

// Round 12
// 238.913 us; speedup vs baseline: 1.0417x; 1.0417x over previous
//
#include <hip/hip_runtime.h>
#include <math.h>

// ---------- types ----------
typedef __attribute__((ext_vector_type(8))) short short8;
typedef __attribute__((ext_vector_type(4))) short short4v;
typedef __attribute__((ext_vector_type(4))) float f32x4;
typedef __attribute__((ext_vector_type(2))) float f32x2;

#if __has_builtin(__builtin_amdgcn_mfma_f32_16x16x16bf16_1k)
#define HAVE_MFMA16 1
#else
#define HAVE_MFMA16 0
#endif

// bf16 RNE helpers
__device__ __forceinline__ short f2bf(float f) {
  union { float f; unsigned u; } x; x.f = f;
  unsigned r = x.u + 0x7fffu + ((x.u >> 16) & 1u);
  return (short)(r >> 16);
}
#if __has_builtin(__builtin_amdgcn_cvt_pk_bf16_f32)
typedef __attribute__((ext_vector_type(2))) __bf16 bf16x2;
__device__ __forceinline__ unsigned pack_bf(float a, float b) {
  union { bf16x2 v; unsigned u; } t;
  t.v = __builtin_amdgcn_cvt_pk_bf16_f32(a, b);
  return t.u;
}
#else
__device__ __forceinline__ unsigned pack_bf(float a, float b) {
  union { float f; unsigned u; } x, y; x.f = a; y.f = b;
  unsigned ra = x.u + 0x7fffu + ((x.u >> 16) & 1u);
  unsigned rb = y.u + 0x7fffu + ((y.u >> 16) & 1u);
  return (ra >> 16) | (rb & 0xffff0000u);
}
#endif
__device__ __forceinline__ float fast_exp2(float x) {
#if __has_builtin(__builtin_amdgcn_exp2f)
  return __builtin_amdgcn_exp2f(x);
#else
  return exp2f(x);
#endif
}
union U4S8 { unsigned u[4]; short8 s; };
union U2S4 { unsigned u[2]; short4v s; };

// async global->LDS, 16B/lane: wave-uniform LDS base, HW scatters lane i at base+i*16B.
__device__ __forceinline__ void async16(const short* g, short* lds_uniform) {
  __builtin_amdgcn_global_load_lds(
      (const __attribute__((address_space(1))) void*)g,
      (__attribute__((address_space(3))) void*)lds_uniform, 16, 0, 0);
}

// ---------- weight convert+transpose: T[n][k] = bf16(W[k][n]), 1024x1024 ----------
__global__ __launch_bounds__(256) void wconv(
    const float* __restrict__ W0, const float* __restrict__ W1,
    const float* __restrict__ W2, const float* __restrict__ W3,
    short* __restrict__ T0, short* __restrict__ T1,
    short* __restrict__ T2, short* __restrict__ T3) {
  const float* W; short* T;
  switch (blockIdx.z) {
    case 0: W = W0; T = T0; break;
    case 1: W = W1; T = T1; break;
    case 2: W = W2; T = T2; break;
    default: W = W3; T = T3; break;
  }
  __shared__ __align__(16) short t[64][72];
  const int tid = threadIdx.x;
  const int x0 = blockIdx.x * 64, y0 = blockIdx.y * 64;
  {
    int rr = tid >> 2, cc = (tid & 3) * 16;
    const float* p = W + (size_t)(x0 + rr) * 1024 + y0 + cc;
    f32x4 v[4];
    v[0] = *(const f32x4*)(p + 0);  v[1] = *(const f32x4*)(p + 4);
    v[2] = *(const f32x4*)(p + 8);  v[3] = *(const f32x4*)(p + 12);
#pragma unroll
    for (int i = 0; i < 4; ++i)
#pragma unroll
      for (int j = 0; j < 4; ++j)
        t[cc + 4 * i + j][rr] = f2bf(v[i][j]);
  }
  __syncthreads();
  {
    int nr = tid >> 2, kc = (tid & 3) * 16;
    short* q = T + (size_t)(y0 + nr) * 1024 + x0 + kc;
    *(short8*)q       = *(const short8*)&t[nr][kc];
    *(short8*)(q + 8) = *(const short8*)&t[nr][kc + 8];
  }
}

// ---------- activation convert: Y = bf16(X), 4M elements each ----------
__global__ __launch_bounds__(256) void aconv(
    const float* __restrict__ X0, const float* __restrict__ X1, const float* __restrict__ X2,
    short* __restrict__ Y0, short* __restrict__ Y1, short* __restrict__ Y2) {
  const float* X; short* Y;
  switch (blockIdx.z) {
    case 0: X = X0; Y = Y0; break;
    case 1: X = X1; Y = Y1; break;
    default: X = X2; Y = Y2; break;
  }
  size_t idx = ((size_t)blockIdx.x * 256 + threadIdx.x) * 16;
  f32x4 v0 = *(const f32x4*)(X + idx + 0);
  f32x4 v1 = *(const f32x4*)(X + idx + 4);
  f32x4 v2 = *(const f32x4*)(X + idx + 8);
  f32x4 v3 = *(const f32x4*)(X + idx + 12);
  U4S8 a, b;
  a.u[0] = pack_bf(v0[0], v0[1]); a.u[1] = pack_bf(v0[2], v0[3]);
  a.u[2] = pack_bf(v1[0], v1[1]); a.u[3] = pack_bf(v1[2], v1[3]);
  b.u[0] = pack_bf(v2[0], v2[1]); b.u[1] = pack_bf(v2[2], v2[3]);
  b.u[2] = pack_bf(v3[0], v3[1]); b.u[3] = pack_bf(v3[2], v3[3]);
  *(short8*)(Y + idx) = a.s;
  *(short8*)(Y + idx + 8) = b.s;
}

// ---------- async GEMM (m97 structure): C = (A@B^T + bias)*scale, all-bf16 in, fp32 acc ----------
template <bool OUT_F32, int BM>
__global__ __launch_bounds__(256) void gemm_async(
    const short* __restrict__ A0, const short* __restrict__ A1, const short* __restrict__ A2,
    const short* __restrict__ B0, const short* __restrict__ B1, const short* __restrict__ B2,
    const float* __restrict__ b0, const float* __restrict__ b1, const float* __restrict__ b2,
    void* __restrict__ C0, void* __restrict__ C1, void* __restrict__ C2,
    float s0, float s1, float s2, int M, int N, int K) {
  const int z = blockIdx.z;
  const short* A    = z == 0 ? A0 : (z == 1 ? A1 : A2);
  const short* B    = z == 0 ? B0 : (z == 1 ? B1 : B2);
  const float* bias = z == 0 ? b0 : (z == 1 ? b1 : b2);
  void*        Cv   = z == 0 ? C0 : (z == 1 ? C1 : C2);
  const float  cs   = z == 0 ? s0 : (z == 1 ? s1 : s2);

  constexpr int MF = BM / 32;
  constexpr int AJ = BM / 64;
  __shared__ __align__(16) short As[BM * 32];
  __shared__ __align__(16) short Bs[128 * 32];
  const int tid = threadIdx.x;
  const int l = tid & 63, w = tid >> 6;
  const int lr = l & 15, lq = l >> 4;
  const int lin = blockIdx.x + (int)gridDim.x * blockIdx.y;
  const int ny = (int)gridDim.y;
  const int yb = lin % ny, xb = lin / ny;
  const int m0 = yb * BM, n0 = xb * 128;
  const int wm = (w >> 1) * (BM / 2), wn = (w & 1) * 64;
  f32x4 acc[MF][4] = {};

  const int lrow = l >> 2, lcol = (l & 3) * 8;
  const short* aptr[AJ];
  short* alds[AJ];
#pragma unroll
  for (int j = 0; j < AJ; ++j) {
    int chunk = w * AJ + j;
    aptr[j] = A + (size_t)(m0 + chunk * 16 + lrow) * K + lcol;
    alds[j] = &As[chunk * 512];
  }
  const short* bptr[2];
  short* blds[2];
#pragma unroll
  for (int j = 0; j < 2; ++j) {
    int chunk = w * 2 + j;
    bptr[j] = B + (size_t)(n0 + chunk * 16 + lrow) * K + lcol;
    blds[j] = &Bs[chunk * 512];
  }

  const int KT = K >> 5;
  for (int kt = 0; kt < KT; ++kt) {
    const int k0 = kt * 32;
    __syncthreads();
#pragma unroll
    for (int j = 0; j < AJ; ++j) async16(aptr[j] + k0, alds[j]);
#pragma unroll
    for (int j = 0; j < 2; ++j) async16(bptr[j] + k0, blds[j]);
    __syncthreads();

    short8 af[MF], bfr[4];
#pragma unroll
    for (int i = 0; i < MF; ++i)
      af[i] = *(const short8*)&As[(wm + i * 16 + lr) * 32 + lq * 8];
#pragma unroll
    for (int i = 0; i < 4; ++i)
      bfr[i] = *(const short8*)&Bs[(wn + i * 16 + lr) * 32 + lq * 8];
#pragma unroll
    for (int mi = 0; mi < MF; ++mi)
#pragma unroll
      for (int ni = 0; ni < 4; ++ni)
        acc[mi][ni] = __builtin_amdgcn_mfma_f32_16x16x32_bf16(af[mi], bfr[ni], acc[mi][ni], 0, 0, 0);
  }

#pragma unroll
  for (int ni = 0; ni < 4; ++ni) {
    int gn = n0 + wn + ni * 16 + lr;
    float bv = bias[gn];
#pragma unroll
    for (int mi = 0; mi < MF; ++mi) {
      int gm = m0 + wm + mi * 16 + lq * 4;
#pragma unroll
      for (int r = 0; r < 4; ++r) {
        float val = (acc[mi][ni][r] + bv) * cs;
        if constexpr (OUT_F32)
          ((float*)Cv)[(size_t)(gm + r) * N + gn] = val;
        else
          ((short*)Cv)[(size_t)(gm + r) * N + gn] = f2bf(val);
      }
    }
  }
}

// ---------- fallback GEMM (round-9 verified): reg-dbuf, A fp32 or bf16 ----------
template <bool A_IS_F32, bool B_IS_BF16, bool OUT_F32, int BM>
__global__ __launch_bounds__(256) void gemm_bias(
    const void* __restrict__ A0, const void* __restrict__ A1, const void* __restrict__ A2,
    const void* __restrict__ B0, const void* __restrict__ B1, const void* __restrict__ B2,
    const float* __restrict__ b0, const float* __restrict__ b1, const float* __restrict__ b2,
    void* __restrict__ C0, void* __restrict__ C1, void* __restrict__ C2,
    float s0, float s1, float s2, int M, int N, int K) {
  const int z = blockIdx.z;
  const void*  Av   = z == 0 ? A0 : (z == 1 ? A1 : A2);
  const void*  Bv   = z == 0 ? B0 : (z == 1 ? B1 : B2);
  const float* bias = z == 0 ? b0 : (z == 1 ? b1 : b2);
  void*        Cv   = z == 0 ? C0 : (z == 1 ? C1 : C2);
  const float  cs   = z == 0 ? s0 : (z == 1 ? s1 : s2);

  constexpr int MF = BM / 32;
  __shared__ __align__(16) short As[BM * 40];
  __shared__ __align__(16) short Bs[128 * 40];
  const int tid = threadIdx.x;
  const int l = tid & 63, w = tid >> 6;
  const int lr = l & 15, lq = l >> 4;
  const int lin = blockIdx.x + (int)gridDim.x * blockIdx.y;
  const int ny = (int)gridDim.y;
  const int yb = lin % ny, xb = lin / ny;
  const int m0 = yb * BM, n0 = xb * 128;
  const int wm = (w >> 1) * (BM / 2), wn = (w & 1) * 64;
  f32x4 acc[MF][4] = {};

  constexpr int TPR = 256 / BM;
  const int ar = tid / TPR, ac = (tid % TPR) * (32 / TPR);
  const int br = tid >> 1, bcc = (tid & 1) * 16;
  const int dp = tid & 63, kb = tid >> 6;

  f32x4 avf[MF];
  short8 avb[BM / 64 > 0 ? BM / 64 : 1];
  short8 bvb[2];
  f32x2 bvf[8];

  auto load_regs = [&](int k0) {
    if constexpr (A_IS_F32) {
      const float* Ap = (const float*)Av + (size_t)(m0 + ar) * K + k0 + ac;
#pragma unroll
      for (int i = 0; i < MF; ++i) avf[i] = *(const f32x4*)(Ap + 4 * i);
    } else {
      const short* Ap = (const short*)Av + (size_t)(m0 + ar) * K + k0 + ac;
#pragma unroll
      for (int i = 0; i < BM / 64; ++i) avb[i] = *(const short8*)(Ap + 8 * i);
    }
    if constexpr (B_IS_BF16) {
      const short* Bp = (const short*)Bv + (size_t)(n0 + br) * K + k0 + bcc;
      bvb[0] = *(const short8*)(Bp + 0);
      bvb[1] = *(const short8*)(Bp + 8);
    } else {
      const float* Bp = (const float*)Bv + (size_t)(k0 + kb * 8) * N + n0 + 2 * dp;
#pragma unroll
      for (int i = 0; i < 4; ++i) {
        bvf[2 * i]     = *(const f32x2*)(Bp + (size_t)(2 * i) * N);
        bvf[2 * i + 1] = *(const f32x2*)(Bp + (size_t)(2 * i + 1) * N);
      }
    }
  };
  auto write_lds = [&]() {
    if constexpr (A_IS_F32) {
#pragma unroll
      for (int j = 0; j < MF / 2; ++j) {
        U4S8 p;
        p.u[0] = pack_bf(avf[2 * j][0], avf[2 * j][1]);
        p.u[1] = pack_bf(avf[2 * j][2], avf[2 * j][3]);
        p.u[2] = pack_bf(avf[2 * j + 1][0], avf[2 * j + 1][1]);
        p.u[3] = pack_bf(avf[2 * j + 1][2], avf[2 * j + 1][3]);
        *(short8*)&As[ar * 40 + ac + 8 * j] = p.s;
      }
    } else {
#pragma unroll
      for (int j = 0; j < BM / 64; ++j)
        *(short8*)&As[ar * 40 + ac + 8 * j] = avb[j];
    }
    if constexpr (B_IS_BF16) {
      *(short8*)&Bs[br * 40 + bcc] = bvb[0];
      *(short8*)&Bs[br * 40 + bcc + 8] = bvb[1];
    } else {
      U4S8 lo, hi;
#pragma unroll
      for (int i = 0; i < 4; ++i) {
        lo.u[i] = pack_bf(bvf[2 * i][0], bvf[2 * i + 1][0]);
        hi.u[i] = pack_bf(bvf[2 * i][1], bvf[2 * i + 1][1]);
      }
      *(short8*)&Bs[(2 * dp) * 40 + kb * 8] = lo.s;
      *(short8*)&Bs[(2 * dp + 1) * 40 + kb * 8] = hi.s;
    }
  };

  load_regs(0);
  const int KT = K >> 5;
  for (int kt = 0; kt < KT; ++kt) {
    write_lds();
    __syncthreads();
    if (kt + 1 < KT) load_regs((kt + 1) * 32);

    short8 af[MF], bfr[4];
#pragma unroll
    for (int i = 0; i < MF; ++i)
      af[i] = *(const short8*)&As[(wm + i * 16 + lr) * 40 + lq * 8];
#pragma unroll
    for (int i = 0; i < 4; ++i)
      bfr[i] = *(const short8*)&Bs[(wn + i * 16 + lr) * 40 + lq * 8];
#pragma unroll
    for (int mi = 0; mi < MF; ++mi)
#pragma unroll
      for (int ni = 0; ni < 4; ++ni)
        acc[mi][ni] = __builtin_amdgcn_mfma_f32_16x16x32_bf16(af[mi], bfr[ni], acc[mi][ni], 0, 0, 0);
    __syncthreads();
  }

#pragma unroll
  for (int ni = 0; ni < 4; ++ni) {
    int gn = n0 + wn + ni * 16 + lr;
    float bv = bias[gn];
#pragma unroll
    for (int mi = 0; mi < MF; ++mi) {
      int gm = m0 + wm + mi * 16 + lq * 4;
#pragma unroll
      for (int r = 0; r < 4; ++r) {
        float val = (acc[mi][ni][r] + bv) * cs;
        if constexpr (OUT_F32)
          ((float*)Cv)[(size_t)(gm + r) * N + gn] = val;
        else
          ((short*)Cv)[(size_t)(gm + r) * N + gn] = f2bf(val);
      }
    }
  }
}

// ---------- flash attention: q-tile 128, double-buffered K/V LDS, ONE barrier/iter ----------
// Q pre-scaled by 0.125*log2(e) -> p = 2^s. S' = K·Q^T (C-layout == mfma16 A-frag layout).
// Vt writes bank-swizzled (block p = (c + (r>>3)) & 7, verified round 11).
// Safety of single barrier: write(buf)@kt+2 is separated from read(buf)@kt by barriers
// B_{kt} and B_{kt+1}; a lagging wave in compute@kt blocks all waves at B_{kt+1}.
__global__ __launch_bounds__(256) void attn128db(
    const short* __restrict__ Q, const short* __restrict__ K,
    const short* __restrict__ V, short* __restrict__ ctx) {
  __shared__ __align__(16) short Ks[2][64][72];   // [buf][kpos][d]
  __shared__ __align__(16) short Vt[2][64][72];   // [buf][d][kpos], block-swizzled
#if !HAVE_MFMA16
  __shared__ __align__(16) short Ps2[4][32][68];
#endif
  const int tid = threadIdx.x, l = tid & 63, w = tid >> 6;
  const int lr = l & 15, lq = l >> 4;
  const int lin = blockIdx.x + 16 * blockIdx.y;
  const int h = lin & 15, qblk = lin >> 4;
  const int b = blockIdx.z, q0 = qblk * 128;
  const size_t bh = (size_t)b * 2048 * 1024 + (size_t)h * 64;
  const short* Kg = K + bh;
  const short* Vg = V + bh;

  short8 qb[2][2];
#pragma unroll
  for (int qf = 0; qf < 2; ++qf)
#pragma unroll
    for (int ks = 0; ks < 2; ++ks)
      qb[qf][ks] = *(const short8*)&Q[bh + (size_t)(q0 + w * 32 + qf * 16 + lr) * 1024 + ks * 32 + lq * 8];

  f32x4 accO[4][2] = {};
  float lpart[2] = {0.f, 0.f};

  const int kr = tid >> 2, kc = (tid & 3) * 16;
  const int vdp = tid & 31, vkb = tid >> 5;
  const int vswz = ((vkb + (vdp >> 2)) & 7) * 8;  // balanced write banks (r11-verified)

  short8 kv0, kv1;
  unsigned vu[8];
  auto load_kv = [&](int kt) {
    const short* Kp = &Kg[(size_t)(kt * 64 + kr) * 1024 + kc];
    kv0 = *(const short8*)(Kp + 0);
    kv1 = *(const short8*)(Kp + 8);
#pragma unroll
    for (int i = 0; i < 8; ++i)
      vu[i] = *(const unsigned*)&Vg[(size_t)(kt * 64 + vkb * 8 + i) * 1024 + vdp * 2];
  };
  auto write_kv = [&](int buf) {
    *(short8*)&Ks[buf][kr][kc] = kv0;
    *(short8*)&Ks[buf][kr][kc + 8] = kv1;
    U4S8 lo, hi;
#pragma unroll
    for (int j = 0; j < 4; ++j) {
      lo.u[j] = (vu[2 * j] & 0xffffu) | (vu[2 * j + 1] << 16);       // d = 2*vdp
      hi.u[j] = (vu[2 * j] >> 16) | (vu[2 * j + 1] & 0xffff0000u);  // d = 2*vdp+1
    }
    *(short8*)&Vt[buf][2 * vdp][vswz] = lo.s;
    *(short8*)&Vt[buf][2 * vdp + 1][vswz] = hi.s;
  };

  load_kv(0);
  for (int kt = 0; kt < 32; ++kt) {
    const int buf = kt & 1;
    write_kv(buf);        // vmcnt wait here: loads issued one full compute-phase ago
    __syncthreads();      // single barrier per iter (see safety note above)
    if (kt + 1 < 32) load_kv(kt + 1);

    // S' = K·Q^T
    short8 ka[4][2];
#pragma unroll
    for (int ni = 0; ni < 4; ++ni)
#pragma unroll
      for (int ks = 0; ks < 2; ++ks)
        ka[ni][ks] = *(const short8*)&Ks[buf][ni * 16 + lr][ks * 32 + lq * 8];
    f32x4 s[4][2] = {};
#pragma unroll
    for (int ni = 0; ni < 4; ++ni)
#pragma unroll
      for (int qf = 0; qf < 2; ++qf) {
        s[ni][qf] = __builtin_amdgcn_mfma_f32_16x16x32_bf16(ka[ni][0], qb[qf][0], s[ni][qf], 0, 0, 0);
        s[ni][qf] = __builtin_amdgcn_mfma_f32_16x16x32_bf16(ka[ni][1], qb[qf][1], s[ni][qf], 0, 0, 0);
      }

    // p = 2^s, pack bf16
    unsigned pk[4][2][2];
#pragma unroll
    for (int ni = 0; ni < 4; ++ni)
#pragma unroll
      for (int qf = 0; qf < 2; ++qf) {
        float p0 = fast_exp2(s[ni][qf][0]);
        float p1 = fast_exp2(s[ni][qf][1]);
        float p2 = fast_exp2(s[ni][qf][2]);
        float p3 = fast_exp2(s[ni][qf][3]);
        lpart[qf] += (p0 + p1) + (p2 + p3);
        pk[ni][qf][0] = pack_bf(p0, p1);
        pk[ni][qf][1] = pack_bf(p2, p3);
      }

#if HAVE_MFMA16
#pragma unroll
    for (int di = 0; di < 4; ++di) {
      const int dR = di * 16 + lr;
      const int ud = 2 * di + (lr >> 3);
#pragma unroll
      for (int ni = 0; ni < 4; ++ni) {
        const int pb = ((2 * ni + (lq >> 1) + ud) & 7) * 8 + (lq & 1) * 4;
        short4v vb = *(const short4v*)&Vt[buf][dR][pb];
#pragma unroll
        for (int qf = 0; qf < 2; ++qf) {
          U2S4 a; a.u[0] = pk[ni][qf][0]; a.u[1] = pk[ni][qf][1];
          accO[di][qf] = __builtin_amdgcn_mfma_f32_16x16x16bf16_1k(a.s, vb, accO[di][qf], 0, 0, 0);
        }
      }
    }
#else
#pragma unroll
    for (int ni = 0; ni < 4; ++ni)
#pragma unroll
      for (int qf = 0; qf < 2; ++qf) {
        unsigned* dst = (unsigned*)&Ps2[w][qf * 16 + lr][16 * ni + 4 * lq];
        dst[0] = pk[ni][qf][0];
        dst[1] = pk[ni][qf][1];
      }
#pragma unroll
    for (int ks = 0; ks < 2; ++ks)
#pragma unroll
      for (int qf = 0; qf < 2; ++qf) {
        const short* src = &Ps2[w][qf * 16 + lr][32 * ks + 8 * lq];
        U4S8 a;
        a.u[0] = ((const unsigned*)src)[0]; a.u[1] = ((const unsigned*)src)[1];
        a.u[2] = ((const unsigned*)src)[2]; a.u[3] = ((const unsigned*)src)[3];
#pragma unroll
        for (int di = 0; di < 4; ++di) {
          const int dR = di * 16 + lr;
          const int ud = 2 * di + (lr >> 3);
          const int pb = ((4 * ks + lq + ud) & 7) * 8;
          short8 vb = *(const short8*)&Vt[buf][dR][pb];
          accO[di][qf] = __builtin_amdgcn_mfma_f32_16x16x32_bf16(a.s, vb, accO[di][qf], 0, 0, 0);
        }
      }
#endif
  }

  // l: combine 4 lq replicas; redistribute to C-layout rows
#pragma unroll
  for (int qf = 0; qf < 2; ++qf) {
    lpart[qf] += __shfl_xor(lpart[qf], 16, 64);
    lpart[qf] += __shfl_xor(lpart[qf], 32, 64);
  }
  float inv[2] = {1.0f / lpart[0], 1.0f / lpart[1]};
  float ir[2][4];
#pragma unroll
  for (int qf = 0; qf < 2; ++qf)
#pragma unroll
    for (int r = 0; r < 4; ++r)
      ir[qf][r] = __shfl(inv[qf], 4 * lq + r, 64);

#pragma unroll
  for (int qf = 0; qf < 2; ++qf)
#pragma unroll
    for (int r = 0; r < 4; ++r) {
      size_t row = bh + (size_t)(q0 + w * 32 + qf * 16 + 4 * lq + r) * 1024;
#pragma unroll
      for (int di = 0; di < 4; ++di)
        ctx[row + di * 16 + lr] = f2bf(accO[di][qf][r] * ir[qf][r]);
    }
}

// ---------- launch ----------
extern "C" void kernel_launch(void* const* d_in, const int* in_sizes, int n_in,
                              void* d_out, int out_size, void* d_ws, size_t ws_size,
                              hipStream_t stream) {
  const void*  query = d_in[0];
  const void*  key   = d_in[1];
  const void*  value = d_in[2];
  const float* Wq = (const float*)d_in[3];
  const float* bq = (const float*)d_in[4];
  const float* Wk = (const float*)d_in[5];
  const float* bk = (const float*)d_in[6];
  const float* Wv = (const float*)d_in[7];
  const float* bv = (const float*)d_in[8];
  const float* Wo = (const float*)d_in[9];
  const float* bo = (const float*)d_in[10];

  short* ws = (short*)d_ws;
  const size_t MT = 4096ull * 1024ull;
  const size_t WSZ = 1024ull * 1024ull;
  const float qscale = 0.125f * 1.4426950408889634f;

  short* Qb = ws;
  short* Vb = ws + MT;
  short* Kb = (short*)d_out;

  const bool turbo = ws_size >= (4 * MT + 4 * WSZ) * sizeof(short);  // 40 MB

  if (turbo) {
    short* Qcv = ws + 2 * MT;
    short* Vcv = ws + 3 * MT;
    short* Kcv = (short*)d_out + MT;
    short* WqT = ws + 4 * MT;
    short* WkT = WqT + WSZ;
    short* WvT = WqT + 2 * WSZ;
    short* WoT = WqT + 3 * WSZ;

    wconv<<<dim3(16, 16, 4), 256, 0, stream>>>(Wq, Wk, Wv, Wo, WqT, WkT, WvT, WoT);
    aconv<<<dim3(1024, 1, 3), 256, 0, stream>>>(
        (const float*)query, (const float*)key, (const float*)value, Qcv, Kcv, Vcv);
    gemm_async<false, 128><<<dim3(8, 32, 3), 256, 0, stream>>>(
        Qcv, Kcv, Vcv, WqT, WkT, WvT, bq, bk, bv, Qb, Kb, Vb,
        qscale, 1.0f, 1.0f, 4096, 1024, 1024);
    attn128db<<<dim3(16, 16, 2), 256, 0, stream>>>(Qb, Kb, Vb, Qb);
    gemm_async<true, 64><<<dim3(8, 64, 1), 256, 0, stream>>>(
        Qb, Qb, Qb, WoT, WoT, WoT, bo, bo, bo, d_out, d_out, d_out,
        1.0f, 1.0f, 1.0f, 4096, 1024, 1024);
    return;
  }

  // ---- fallback: round-9 verified path ----
  const bool roomy = ws_size >= (2 * MT + 4 * WSZ) * sizeof(short);
  short *WqT, *WkT, *WvT, *WoT;
  if (roomy) {
    short* base = ws + 2 * MT;
    WqT = base; WkT = base + WSZ; WvT = base + 2 * WSZ; WoT = base + 3 * WSZ;
  } else {
    short* tail = (short*)d_out + MT;
    WqT = tail; WkT = tail + WSZ; WvT = tail + 2 * WSZ; WoT = nullptr;
  }

  wconv<<<dim3(16, 16, roomy ? 4 : 3), 256, 0, stream>>>(
      Wq, Wk, Wv, Wo, WqT, WkT, WvT, roomy ? WoT : WvT);

  gemm_bias<true, true, false, 128><<<dim3(8, 32, 3), 256, 0, stream>>>(
      query, key, value, WqT, WkT, WvT, bq, bk, bv, Qb, Kb, Vb,
      qscale, 1.0f, 1.0f, 4096, 1024, 1024);

  attn128db<<<dim3(16, 16, 2), 256, 0, stream>>>(Qb, Kb, Vb, Qb);

  if (roomy)
    gemm_bias<false, true, true, 64><<<dim3(8, 64, 1), 256, 0, stream>>>(
        Qb, Qb, Qb, WoT, WoT, WoT, bo, bo, bo, d_out, d_out, d_out,
        1.0f, 1.0f, 1.0f, 4096, 1024, 1024);
  else
    gemm_bias<false, false, true, 64><<<dim3(8, 64, 1), 256, 0, stream>>>(
        Qb, Qb, Qb, Wo, Wo, Wo, bo, bo, bo, d_out, d_out, d_out,
        1.0f, 1.0f, 1.0f, 4096, 1024, 1024);
}

// Round 13
// 234.133 us; speedup vs baseline: 1.0629x; 1.0204x over previous
//
#include <hip/hip_runtime.h>
#include <math.h>

// ---------- types ----------
typedef __attribute__((ext_vector_type(8))) short short8;
typedef __attribute__((ext_vector_type(4))) short short4v;
typedef __attribute__((ext_vector_type(4))) float f32x4;
typedef __attribute__((ext_vector_type(2))) float f32x2;

#if __has_builtin(__builtin_amdgcn_mfma_f32_16x16x16bf16_1k)
#define HAVE_MFMA16 1
#else
#define HAVE_MFMA16 0
#endif

// bf16 helpers
__device__ __forceinline__ short f2bf(float f) {
  union { float f; unsigned u; } x; x.f = f;
  unsigned r = x.u + 0x7fffu + ((x.u >> 16) & 1u);
  return (short)(r >> 16);
}
__device__ __forceinline__ float bf2f(short u) {
  union { unsigned u; float f; } x;
  x.u = ((unsigned)(unsigned short)u) << 16;
  return x.f;
}
#if __has_builtin(__builtin_amdgcn_cvt_pk_bf16_f32)
typedef __attribute__((ext_vector_type(2))) __bf16 bf16x2;
__device__ __forceinline__ unsigned pack_bf(float a, float b) {
  union { bf16x2 v; unsigned u; } t;
  t.v = __builtin_amdgcn_cvt_pk_bf16_f32(a, b);
  return t.u;
}
#else
__device__ __forceinline__ unsigned pack_bf(float a, float b) {
  union { float f; unsigned u; } x, y; x.f = a; y.f = b;
  unsigned ra = x.u + 0x7fffu + ((x.u >> 16) & 1u);
  unsigned rb = y.u + 0x7fffu + ((y.u >> 16) & 1u);
  return (ra >> 16) | (rb & 0xffff0000u);
}
#endif
__device__ __forceinline__ float fast_exp2(float x) {
#if __has_builtin(__builtin_amdgcn_exp2f)
  return __builtin_amdgcn_exp2f(x);
#else
  return exp2f(x);
#endif
}
union U4S8 { unsigned u[4]; short8 s; };
union U2S4 { unsigned u[2]; short4v s; };

// async global->LDS, 16B/lane: wave-uniform LDS base, HW scatters lane i at base+i*16B.
__device__ __forceinline__ void async16(const short* g, short* lds_uniform) {
  __builtin_amdgcn_global_load_lds(
      (const __attribute__((address_space(1))) void*)g,
      (__attribute__((address_space(3))) void*)lds_uniform, 16, 0, 0);
}

// ---------- weight convert+transpose: T[n][k] = bf16(W[k][n]), 1024x1024 ----------
__global__ __launch_bounds__(256) void wconv(
    const float* __restrict__ W0, const float* __restrict__ W1,
    const float* __restrict__ W2, const float* __restrict__ W3,
    short* __restrict__ T0, short* __restrict__ T1,
    short* __restrict__ T2, short* __restrict__ T3) {
  const float* W; short* T;
  switch (blockIdx.z) {
    case 0: W = W0; T = T0; break;
    case 1: W = W1; T = T1; break;
    case 2: W = W2; T = T2; break;
    default: W = W3; T = T3; break;
  }
  __shared__ __align__(16) short t[64][72];
  const int tid = threadIdx.x;
  const int x0 = blockIdx.x * 64, y0 = blockIdx.y * 64;
  {
    int rr = tid >> 2, cc = (tid & 3) * 16;
    const float* p = W + (size_t)(x0 + rr) * 1024 + y0 + cc;
    f32x4 v[4];
    v[0] = *(const f32x4*)(p + 0);  v[1] = *(const f32x4*)(p + 4);
    v[2] = *(const f32x4*)(p + 8);  v[3] = *(const f32x4*)(p + 12);
#pragma unroll
    for (int i = 0; i < 4; ++i)
#pragma unroll
      for (int j = 0; j < 4; ++j)
        t[cc + 4 * i + j][rr] = f2bf(v[i][j]);
  }
  __syncthreads();
  {
    int nr = tid >> 2, kc = (tid & 3) * 16;
    short* q = T + (size_t)(y0 + nr) * 1024 + x0 + kc;
    *(short8*)q       = *(const short8*)&t[nr][kc];
    *(short8*)(q + 8) = *(const short8*)&t[nr][kc + 8];
  }
}

// ---------- activation convert: Y = bf16(X), 4M elements each ----------
__global__ __launch_bounds__(256) void aconv(
    const float* __restrict__ X0, const float* __restrict__ X1, const float* __restrict__ X2,
    short* __restrict__ Y0, short* __restrict__ Y1, short* __restrict__ Y2) {
  const float* X; short* Y;
  switch (blockIdx.z) {
    case 0: X = X0; Y = Y0; break;
    case 1: X = X1; Y = Y1; break;
    default: X = X2; Y = Y2; break;
  }
  size_t idx = ((size_t)blockIdx.x * 256 + threadIdx.x) * 16;
  f32x4 v0 = *(const f32x4*)(X + idx + 0);
  f32x4 v1 = *(const f32x4*)(X + idx + 4);
  f32x4 v2 = *(const f32x4*)(X + idx + 8);
  f32x4 v3 = *(const f32x4*)(X + idx + 12);
  U4S8 a, b;
  a.u[0] = pack_bf(v0[0], v0[1]); a.u[1] = pack_bf(v0[2], v0[3]);
  a.u[2] = pack_bf(v1[0], v1[1]); a.u[3] = pack_bf(v1[2], v1[3]);
  b.u[0] = pack_bf(v2[0], v2[1]); b.u[1] = pack_bf(v2[2], v2[3]);
  b.u[2] = pack_bf(v3[0], v3[1]); b.u[3] = pack_bf(v3[2], v3[3]);
  *(short8*)(Y + idx) = a.s;
  *(short8*)(Y + idx + 8) = b.s;
}

// ---------- async GEMM, single-barrier LDS double-buffer ----------
// C = (A@B^T + bias)*scale, all-bf16 in, fp32 acc. BM x 128 tile, BK=32, 4 waves.
// Safety: asyncs into buf issued at iter kt-1 (after its barrier) are drained by the
// vmcnt(0) the compiler emits before iter kt's barrier -- one full compute phase later.
template <bool OUT_F32, int BM>
__global__ __launch_bounds__(256) void gemm_async(
    const short* __restrict__ A0, const short* __restrict__ A1, const short* __restrict__ A2,
    const short* __restrict__ B0, const short* __restrict__ B1, const short* __restrict__ B2,
    const float* __restrict__ b0, const float* __restrict__ b1, const float* __restrict__ b2,
    void* __restrict__ C0, void* __restrict__ C1, void* __restrict__ C2,
    float s0, float s1, float s2, int M, int N, int K) {
  const int z = blockIdx.z;
  const short* A    = z == 0 ? A0 : (z == 1 ? A1 : A2);
  const short* B    = z == 0 ? B0 : (z == 1 ? B1 : B2);
  const float* bias = z == 0 ? b0 : (z == 1 ? b1 : b2);
  void*        Cv   = z == 0 ? C0 : (z == 1 ? C1 : C2);
  const float  cs   = z == 0 ? s0 : (z == 1 ? s1 : s2);

  constexpr int MF = BM / 32;
  constexpr int AJ = BM / 64;
  __shared__ __align__(16) short As[2][BM * 32];
  __shared__ __align__(16) short Bs[2][128 * 32];
  const int tid = threadIdx.x;
  const int l = tid & 63, w = tid >> 6;
  const int lr = l & 15, lq = l >> 4;
  const int lin = blockIdx.x + (int)gridDim.x * blockIdx.y;
  const int ny = (int)gridDim.y;
  const int yb = lin % ny, xb = lin / ny;
  const int m0 = yb * BM, n0 = xb * 128;
  const int wm = (w >> 1) * (BM / 2), wn = (w & 1) * 64;
  f32x4 acc[MF][4] = {};

  const int lrow = l >> 2, lcol = (l & 3) * 8;
  const short* aptr[AJ];
  short* alds[AJ];
#pragma unroll
  for (int j = 0; j < AJ; ++j) {
    int chunk = w * AJ + j;
    aptr[j] = A + (size_t)(m0 + chunk * 16 + lrow) * K + lcol;
    alds[j] = &As[0][chunk * 512];
  }
  const short* bptr[2];
  short* blds[2];
#pragma unroll
  for (int j = 0; j < 2; ++j) {
    int chunk = w * 2 + j;
    bptr[j] = B + (size_t)(n0 + chunk * 16 + lrow) * K + lcol;
    blds[j] = &Bs[0][chunk * 512];
  }

  // prologue: stage kt=0 into buf 0
#pragma unroll
  for (int j = 0; j < AJ; ++j) async16(aptr[j], alds[j]);
#pragma unroll
  for (int j = 0; j < 2; ++j) async16(bptr[j], blds[j]);

  const int KT = K >> 5;
  for (int kt = 0; kt < KT; ++kt) {
    const int buf = kt & 1;
    __syncthreads();  // drains buf's asyncs (issued one compute-phase ago); fences buf^1 readers
    if (kt + 1 < KT) {
      const int k1 = (kt + 1) * 32;
      const int off = (buf ^ 1) ? 0 : 1;  // target buffer = buf^1
      short* at = (buf ^ 1) ? (short*)&As[1][0] : (short*)&As[0][0];
      short* bt = (buf ^ 1) ? (short*)&Bs[1][0] : (short*)&Bs[0][0];
      (void)off;
#pragma unroll
      for (int j = 0; j < AJ; ++j)
        async16(aptr[j] + k1, at + (alds[j] - &As[0][0]));
#pragma unroll
      for (int j = 0; j < 2; ++j)
        async16(bptr[j] + k1, bt + (blds[j] - &Bs[0][0]));
    }

    short8 af[MF], bfr[4];
#pragma unroll
    for (int i = 0; i < MF; ++i)
      af[i] = *(const short8*)&As[buf][(wm + i * 16 + lr) * 32 + lq * 8];
#pragma unroll
    for (int i = 0; i < 4; ++i)
      bfr[i] = *(const short8*)&Bs[buf][(wn + i * 16 + lr) * 32 + lq * 8];
#pragma unroll
    for (int mi = 0; mi < MF; ++mi)
#pragma unroll
      for (int ni = 0; ni < 4; ++ni)
        acc[mi][ni] = __builtin_amdgcn_mfma_f32_16x16x32_bf16(af[mi], bfr[ni], acc[mi][ni], 0, 0, 0);
  }

  // epilogue: C/D layout col=lane&15, row=(lane>>4)*4+reg
#pragma unroll
  for (int ni = 0; ni < 4; ++ni) {
    int gn = n0 + wn + ni * 16 + lr;
    float bv = bias[gn];
#pragma unroll
    for (int mi = 0; mi < MF; ++mi) {
      int gm = m0 + wm + mi * 16 + lq * 4;
#pragma unroll
      for (int r = 0; r < 4; ++r) {
        float val = (acc[mi][ni][r] + bv) * cs;
        if constexpr (OUT_F32)
          ((float*)Cv)[(size_t)(gm + r) * N + gn] = val;
        else
          ((short*)Cv)[(size_t)(gm + r) * N + gn] = f2bf(val);
      }
    }
  }
}

// ---------- fallback GEMM (round-9 verified): reg-dbuf, A fp32 or bf16 ----------
template <bool A_IS_F32, bool B_IS_BF16, bool OUT_F32, int BM>
__global__ __launch_bounds__(256) void gemm_bias(
    const void* __restrict__ A0, const void* __restrict__ A1, const void* __restrict__ A2,
    const void* __restrict__ B0, const void* __restrict__ B1, const void* __restrict__ B2,
    const float* __restrict__ b0, const float* __restrict__ b1, const float* __restrict__ b2,
    void* __restrict__ C0, void* __restrict__ C1, void* __restrict__ C2,
    float s0, float s1, float s2, int M, int N, int K) {
  const int z = blockIdx.z;
  const void*  Av   = z == 0 ? A0 : (z == 1 ? A1 : A2);
  const void*  Bv   = z == 0 ? B0 : (z == 1 ? B1 : B2);
  const float* bias = z == 0 ? b0 : (z == 1 ? b1 : b2);
  void*        Cv   = z == 0 ? C0 : (z == 1 ? C1 : C2);
  const float  cs   = z == 0 ? s0 : (z == 1 ? s1 : s2);

  constexpr int MF = BM / 32;
  __shared__ __align__(16) short As[BM * 40];
  __shared__ __align__(16) short Bs[128 * 40];
  const int tid = threadIdx.x;
  const int l = tid & 63, w = tid >> 6;
  const int lr = l & 15, lq = l >> 4;
  const int lin = blockIdx.x + (int)gridDim.x * blockIdx.y;
  const int ny = (int)gridDim.y;
  const int yb = lin % ny, xb = lin / ny;
  const int m0 = yb * BM, n0 = xb * 128;
  const int wm = (w >> 1) * (BM / 2), wn = (w & 1) * 64;
  f32x4 acc[MF][4] = {};

  constexpr int TPR = 256 / BM;
  const int ar = tid / TPR, ac = (tid % TPR) * (32 / TPR);
  const int br = tid >> 1, bcc = (tid & 1) * 16;
  const int dp = tid & 63, kb = tid >> 6;

  f32x4 avf[MF];
  short8 avb[BM / 64 > 0 ? BM / 64 : 1];
  short8 bvb[2];
  f32x2 bvf[8];

  auto load_regs = [&](int k0) {
    if constexpr (A_IS_F32) {
      const float* Ap = (const float*)Av + (size_t)(m0 + ar) * K + k0 + ac;
#pragma unroll
      for (int i = 0; i < MF; ++i) avf[i] = *(const f32x4*)(Ap + 4 * i);
    } else {
      const short* Ap = (const short*)Av + (size_t)(m0 + ar) * K + k0 + ac;
#pragma unroll
      for (int i = 0; i < BM / 64; ++i) avb[i] = *(const short8*)(Ap + 8 * i);
    }
    if constexpr (B_IS_BF16) {
      const short* Bp = (const short*)Bv + (size_t)(n0 + br) * K + k0 + bcc;
      bvb[0] = *(const short8*)(Bp + 0);
      bvb[1] = *(const short8*)(Bp + 8);
    } else {
      const float* Bp = (const float*)Bv + (size_t)(k0 + kb * 8) * N + n0 + 2 * dp;
#pragma unroll
      for (int i = 0; i < 4; ++i) {
        bvf[2 * i]     = *(const f32x2*)(Bp + (size_t)(2 * i) * N);
        bvf[2 * i + 1] = *(const f32x2*)(Bp + (size_t)(2 * i + 1) * N);
      }
    }
  };
  auto write_lds = [&]() {
    if constexpr (A_IS_F32) {
#pragma unroll
      for (int j = 0; j < MF / 2; ++j) {
        U4S8 p;
        p.u[0] = pack_bf(avf[2 * j][0], avf[2 * j][1]);
        p.u[1] = pack_bf(avf[2 * j][2], avf[2 * j][3]);
        p.u[2] = pack_bf(avf[2 * j + 1][0], avf[2 * j + 1][1]);
        p.u[3] = pack_bf(avf[2 * j + 1][2], avf[2 * j + 1][3]);
        *(short8*)&As[ar * 40 + ac + 8 * j] = p.s;
      }
    } else {
#pragma unroll
      for (int j = 0; j < BM / 64; ++j)
        *(short8*)&As[ar * 40 + ac + 8 * j] = avb[j];
    }
    if constexpr (B_IS_BF16) {
      *(short8*)&Bs[br * 40 + bcc] = bvb[0];
      *(short8*)&Bs[br * 40 + bcc + 8] = bvb[1];
    } else {
      U4S8 lo, hi;
#pragma unroll
      for (int i = 0; i < 4; ++i) {
        lo.u[i] = pack_bf(bvf[2 * i][0], bvf[2 * i + 1][0]);
        hi.u[i] = pack_bf(bvf[2 * i][1], bvf[2 * i + 1][1]);
      }
      *(short8*)&Bs[(2 * dp) * 40 + kb * 8] = lo.s;
      *(short8*)&Bs[(2 * dp + 1) * 40 + kb * 8] = hi.s;
    }
  };

  load_regs(0);
  const int KT = K >> 5;
  for (int kt = 0; kt < KT; ++kt) {
    write_lds();
    __syncthreads();
    if (kt + 1 < KT) load_regs((kt + 1) * 32);

    short8 af[MF], bfr[4];
#pragma unroll
    for (int i = 0; i < MF; ++i)
      af[i] = *(const short8*)&As[(wm + i * 16 + lr) * 40 + lq * 8];
#pragma unroll
    for (int i = 0; i < 4; ++i)
      bfr[i] = *(const short8*)&Bs[(wn + i * 16 + lr) * 40 + lq * 8];
#pragma unroll
    for (int mi = 0; mi < MF; ++mi)
#pragma unroll
      for (int ni = 0; ni < 4; ++ni)
        acc[mi][ni] = __builtin_amdgcn_mfma_f32_16x16x32_bf16(af[mi], bfr[ni], acc[mi][ni], 0, 0, 0);
    __syncthreads();
  }

#pragma unroll
  for (int ni = 0; ni < 4; ++ni) {
    int gn = n0 + wn + ni * 16 + lr;
    float bv = bias[gn];
#pragma unroll
    for (int mi = 0; mi < MF; ++mi) {
      int gm = m0 + wm + mi * 16 + lq * 4;
#pragma unroll
      for (int r = 0; r < 4; ++r) {
        float val = (acc[mi][ni][r] + bv) * cs;
        if constexpr (OUT_F32)
          ((float*)Cv)[(size_t)(gm + r) * N + gn] = val;
        else
          ((short*)Cv)[(size_t)(gm + r) * N + gn] = f2bf(val);
      }
    }
  }
}

// ---------- flash attention: q-tile 128, LDS dbuf, one barrier/iter, optional 2-way K-split ----------
// Q pre-scaled by 0.125*log2(e) -> p = 2^s. S' = K·Q^T (C-layout == mfma16 A-frag layout).
// SPLIT: grid.z = 4 (b = z>>1, half = z&1); each block does 16 k-tiles, writes
// unnormalized bf16 O-partial + fp32 row-sums; merge kernel divides.
template <bool SPLIT>
__global__ __launch_bounds__(256) void attn128db(
    const short* __restrict__ Q, const short* __restrict__ K,
    const short* __restrict__ V, short* __restrict__ ctx,
    short* __restrict__ O0, short* __restrict__ O1, float* __restrict__ lbuf) {
  __shared__ __align__(16) short Ks[2][64][72];   // [buf][kpos][d]
  __shared__ __align__(16) short Vt[2][64][72];   // [buf][d][kpos], block-swizzled
#if !HAVE_MFMA16
  __shared__ __align__(16) short Ps2[4][32][68];
#endif
  const int tid = threadIdx.x, l = tid & 63, w = tid >> 6;
  const int lr = l & 15, lq = l >> 4;
  const int lin = blockIdx.x + 16 * blockIdx.y;
  const int h = lin & 15, qblk = lin >> 4;
  const int z = blockIdx.z;
  const int b = SPLIT ? (z >> 1) : z;
  const int half = SPLIT ? (z & 1) : 0;
  const int kt0 = SPLIT ? half * 16 : 0;
  const int KTN = SPLIT ? 16 : 32;
  const int q0 = qblk * 128;
  const size_t bh = (size_t)b * 2048 * 1024 + (size_t)h * 64;
  const short* Kg = K + bh;
  const short* Vg = V + bh;

  short8 qb[2][2];
#pragma unroll
  for (int qf = 0; qf < 2; ++qf)
#pragma unroll
    for (int ks = 0; ks < 2; ++ks)
      qb[qf][ks] = *(const short8*)&Q[bh + (size_t)(q0 + w * 32 + qf * 16 + lr) * 1024 + ks * 32 + lq * 8];

  f32x4 accO[4][2] = {};
  float lpart[2] = {0.f, 0.f};

  const int kr = tid >> 2, kc = (tid & 3) * 16;
  const int vdp = tid & 31, vkb = tid >> 5;
  const int vswz = ((vkb + (vdp >> 2)) & 7) * 8;  // balanced write banks (r11/r12-verified)

  short8 kv0, kv1;
  unsigned vu[8];
  auto load_kv = [&](int kt) {
    const short* Kp = &Kg[(size_t)(kt * 64 + kr) * 1024 + kc];
    kv0 = *(const short8*)(Kp + 0);
    kv1 = *(const short8*)(Kp + 8);
#pragma unroll
    for (int i = 0; i < 8; ++i)
      vu[i] = *(const unsigned*)&Vg[(size_t)(kt * 64 + vkb * 8 + i) * 1024 + vdp * 2];
  };
  auto write_kv = [&](int buf) {
    *(short8*)&Ks[buf][kr][kc] = kv0;
    *(short8*)&Ks[buf][kr][kc + 8] = kv1;
    U4S8 lo, hi;
#pragma unroll
    for (int j = 0; j < 4; ++j) {
      lo.u[j] = (vu[2 * j] & 0xffffu) | (vu[2 * j + 1] << 16);       // d = 2*vdp
      hi.u[j] = (vu[2 * j] >> 16) | (vu[2 * j + 1] & 0xffff0000u);  // d = 2*vdp+1
    }
    *(short8*)&Vt[buf][2 * vdp][vswz] = lo.s;
    *(short8*)&Vt[buf][2 * vdp + 1][vswz] = hi.s;
  };

  load_kv(kt0);
  for (int i = 0; i < KTN; ++i) {
    const int buf = i & 1;
    write_kv(buf);        // vmcnt wait: loads issued one full compute-phase ago
    __syncthreads();      // single barrier per iter (r12-verified structure)
    if (i + 1 < KTN) load_kv(kt0 + i + 1);

    short8 ka[4][2];
#pragma unroll
    for (int ni = 0; ni < 4; ++ni)
#pragma unroll
      for (int ks = 0; ks < 2; ++ks)
        ka[ni][ks] = *(const short8*)&Ks[buf][ni * 16 + lr][ks * 32 + lq * 8];
    f32x4 s[4][2] = {};
#pragma unroll
    for (int ni = 0; ni < 4; ++ni)
#pragma unroll
      for (int qf = 0; qf < 2; ++qf) {
        s[ni][qf] = __builtin_amdgcn_mfma_f32_16x16x32_bf16(ka[ni][0], qb[qf][0], s[ni][qf], 0, 0, 0);
        s[ni][qf] = __builtin_amdgcn_mfma_f32_16x16x32_bf16(ka[ni][1], qb[qf][1], s[ni][qf], 0, 0, 0);
      }

    unsigned pk[4][2][2];
#pragma unroll
    for (int ni = 0; ni < 4; ++ni)
#pragma unroll
      for (int qf = 0; qf < 2; ++qf) {
        float p0 = fast_exp2(s[ni][qf][0]);
        float p1 = fast_exp2(s[ni][qf][1]);
        float p2 = fast_exp2(s[ni][qf][2]);
        float p3 = fast_exp2(s[ni][qf][3]);
        lpart[qf] += (p0 + p1) + (p2 + p3);
        pk[ni][qf][0] = pack_bf(p0, p1);
        pk[ni][qf][1] = pack_bf(p2, p3);
      }

#if HAVE_MFMA16
#pragma unroll
    for (int di = 0; di < 4; ++di) {
      const int dR = di * 16 + lr;
      const int ud = 2 * di + (lr >> 3);
#pragma unroll
      for (int ni = 0; ni < 4; ++ni) {
        const int pb = ((2 * ni + (lq >> 1) + ud) & 7) * 8 + (lq & 1) * 4;
        short4v vb = *(const short4v*)&Vt[buf][dR][pb];
#pragma unroll
        for (int qf = 0; qf < 2; ++qf) {
          U2S4 a; a.u[0] = pk[ni][qf][0]; a.u[1] = pk[ni][qf][1];
          accO[di][qf] = __builtin_amdgcn_mfma_f32_16x16x16bf16_1k(a.s, vb, accO[di][qf], 0, 0, 0);
        }
      }
    }
#else
#pragma unroll
    for (int ni = 0; ni < 4; ++ni)
#pragma unroll
      for (int qf = 0; qf < 2; ++qf) {
        unsigned* dst = (unsigned*)&Ps2[w][qf * 16 + lr][16 * ni + 4 * lq];
        dst[0] = pk[ni][qf][0];
        dst[1] = pk[ni][qf][1];
      }
#pragma unroll
    for (int ks = 0; ks < 2; ++ks)
#pragma unroll
      for (int qf = 0; qf < 2; ++qf) {
        const short* src = &Ps2[w][qf * 16 + lr][32 * ks + 8 * lq];
        U4S8 a;
        a.u[0] = ((const unsigned*)src)[0]; a.u[1] = ((const unsigned*)src)[1];
        a.u[2] = ((const unsigned*)src)[2]; a.u[3] = ((const unsigned*)src)[3];
#pragma unroll
        for (int di = 0; di < 4; ++di) {
          const int dR = di * 16 + lr;
          const int ud = 2 * di + (lr >> 3);
          const int pb = ((4 * ks + lq + ud) & 7) * 8;
          short8 vb = *(const short8*)&Vt[buf][dR][pb];
          accO[di][qf] = __builtin_amdgcn_mfma_f32_16x16x32_bf16(a.s, vb, accO[di][qf], 0, 0, 0);
        }
      }
#endif
  }

  // combine the 4 lq replicas of lpart -> each lane holds l[q=lr] per qf
#pragma unroll
  for (int qf = 0; qf < 2; ++qf) {
    lpart[qf] += __shfl_xor(lpart[qf], 16, 64);
    lpart[qf] += __shfl_xor(lpart[qf], 32, 64);
  }

  if constexpr (SPLIT) {
    // write raw O partial (bf16) + l partial (fp32)
    short* Op = half ? O1 : O0;
    if (lq == 0) {
      float* lb = lbuf + ((size_t)((half * 2 + b) * 16 + h)) * 2048;
      lb[q0 + w * 32 + lr] = lpart[0];
      lb[q0 + w * 32 + 16 + lr] = lpart[1];
    }
#pragma unroll
    for (int qf = 0; qf < 2; ++qf)
#pragma unroll
      for (int r = 0; r < 4; ++r) {
        size_t row = bh + (size_t)(q0 + w * 32 + qf * 16 + 4 * lq + r) * 1024;
#pragma unroll
        for (int di = 0; di < 4; ++di)
          Op[row + di * 16 + lr] = f2bf(accO[di][qf][r]);
      }
  } else {
    float inv[2] = {1.0f / lpart[0], 1.0f / lpart[1]};
    float ir[2][4];
#pragma unroll
    for (int qf = 0; qf < 2; ++qf)
#pragma unroll
      for (int r = 0; r < 4; ++r)
        ir[qf][r] = __shfl(inv[qf], 4 * lq + r, 64);
#pragma unroll
    for (int qf = 0; qf < 2; ++qf)
#pragma unroll
      for (int r = 0; r < 4; ++r) {
        size_t row = bh + (size_t)(q0 + w * 32 + qf * 16 + 4 * lq + r) * 1024;
#pragma unroll
        for (int di = 0; di < 4; ++di)
          ctx[row + di * 16 + lr] = f2bf(accO[di][qf][r] * ir[qf][r]);
      }
  }
}

// ---------- merge: ctx = (O0 + O1) / (l0 + l1), 4M elems, 8/thread ----------
__global__ __launch_bounds__(256) void merge_attn(
    const short* __restrict__ O0, const short* __restrict__ O1,
    const float* __restrict__ lbuf, short* __restrict__ ctx) {
  size_t i = ((size_t)blockIdx.x * 256 + threadIdx.x) * 8;
  int rq = (int)(i >> 10);          // global row 0..4095
  int b = rq >> 11, q = rq & 2047;
  int h = ((int)i & 1023) >> 6;
  float l0 = lbuf[((size_t)((0 + b) * 16 + h)) * 2048 + q];          // half 0: (0*2+b)
  float l1 = lbuf[((size_t)((2 + b) * 16 + h)) * 2048 + q];          // half 1: (1*2+b)
  float inv = 1.0f / (l0 + l1);
  short8 a = *(const short8*)(O0 + i);
  short8 c = *(const short8*)(O1 + i);
  U4S8 o;
#pragma unroll
  for (int j = 0; j < 4; ++j) {
    float x0 = (bf2f(a[2 * j]) + bf2f(c[2 * j])) * inv;
    float x1 = (bf2f(a[2 * j + 1]) + bf2f(c[2 * j + 1])) * inv;
    o.u[j] = pack_bf(x0, x1);
  }
  *(short8*)(ctx + i) = o.s;
}

// ---------- launch ----------
extern "C" void kernel_launch(void* const* d_in, const int* in_sizes, int n_in,
                              void* d_out, int out_size, void* d_ws, size_t ws_size,
                              hipStream_t stream) {
  const void*  query = d_in[0];
  const void*  key   = d_in[1];
  const void*  value = d_in[2];
  const float* Wq = (const float*)d_in[3];
  const float* bq = (const float*)d_in[4];
  const float* Wk = (const float*)d_in[5];
  const float* bk = (const float*)d_in[6];
  const float* Wv = (const float*)d_in[7];
  const float* bv = (const float*)d_in[8];
  const float* Wo = (const float*)d_in[9];
  const float* bo = (const float*)d_in[10];

  short* ws = (short*)d_ws;
  const size_t MT = 4096ull * 1024ull;
  const size_t WSZ = 1024ull * 1024ull;
  const float qscale = 0.125f * 1.4426950408889634f;

  short* Qb = ws;
  short* Vb = ws + MT;
  short* Kb = (short*)d_out;

  const bool turbo = ws_size >= (4 * MT + 4 * WSZ) * sizeof(short);  // 40 MB

  if (turbo) {
    short* Qcv = ws + 2 * MT;       // QKV inputs; dead after QKV GEMM -> O-partial 0
    short* Vcv = ws + 3 * MT;       // ... -> O-partial 1
    short* Kcv = (short*)d_out + MT;
    short* WqT = ws + 4 * MT;
    short* WkT = WqT + WSZ;
    short* WvT = WqT + 2 * WSZ;
    short* WoT = WqT + 3 * WSZ;
    float* lbuf = (float*)Kcv;      // 512 KB in dead Kcv region (d_out[8..16MB))

    wconv<<<dim3(16, 16, 4), 256, 0, stream>>>(Wq, Wk, Wv, Wo, WqT, WkT, WvT, WoT);
    aconv<<<dim3(1024, 1, 3), 256, 0, stream>>>(
        (const float*)query, (const float*)key, (const float*)value, Qcv, Kcv, Vcv);
    gemm_async<false, 128><<<dim3(8, 32, 3), 256, 0, stream>>>(
        Qcv, Kcv, Vcv, WqT, WkT, WvT, bq, bk, bv, Qb, Kb, Vb,
        qscale, 1.0f, 1.0f, 4096, 1024, 1024);
    // 2-way K-split attention: 1024 blocks = 4/CU; partials into dead Qcv/Vcv
    attn128db<true><<<dim3(16, 16, 4), 256, 0, stream>>>(
        Qb, Kb, Vb, nullptr, Qcv, Vcv, lbuf);
    merge_attn<<<dim3(2048), 256, 0, stream>>>(Qcv, Vcv, lbuf, Qb);
    gemm_async<true, 64><<<dim3(8, 64, 1), 256, 0, stream>>>(
        Qb, Qb, Qb, WoT, WoT, WoT, bo, bo, bo, d_out, d_out, d_out,
        1.0f, 1.0f, 1.0f, 4096, 1024, 1024);
    return;
  }

  // ---- fallback: round-9 verified path ----
  const bool roomy = ws_size >= (2 * MT + 4 * WSZ) * sizeof(short);
  short *WqT, *WkT, *WvT, *WoT;
  if (roomy) {
    short* base = ws + 2 * MT;
    WqT = base; WkT = base + WSZ; WvT = base + 2 * WSZ; WoT = base + 3 * WSZ;
  } else {
    short* tail = (short*)d_out + MT;
    WqT = tail; WkT = tail + WSZ; WvT = tail + 2 * WSZ; WoT = nullptr;
  }

  wconv<<<dim3(16, 16, roomy ? 4 : 3), 256, 0, stream>>>(
      Wq, Wk, Wv, Wo, WqT, WkT, WvT, roomy ? WoT : WvT);

  gemm_bias<true, true, false, 128><<<dim3(8, 32, 3), 256, 0, stream>>>(
      query, key, value, WqT, WkT, WvT, bq, bk, bv, Qb, Kb, Vb,
      qscale, 1.0f, 1.0f, 4096, 1024, 1024);

  attn128db<false><<<dim3(16, 16, 2), 256, 0, stream>>>(
      Qb, Kb, Vb, Qb, nullptr, nullptr, nullptr);

  if (roomy)
    gemm_bias<false, true, true, 64><<<dim3(8, 64, 1), 256, 0, stream>>>(
        Qb, Qb, Qb, WoT, WoT, WoT, bo, bo, bo, d_out, d_out, d_out,
        1.0f, 1.0f, 1.0f, 4096, 1024, 1024);
  else
    gemm_bias<false, false, true, 64><<<dim3(8, 64, 1), 256, 0, stream>>>(
        Qb, Qb, Qb, Wo, Wo, Wo, bo, bo, bo, d_out, d_out, d_out,
        1.0f, 1.0f, 1.0f, 4096, 1024, 1024);
}